// Round 7
// baseline (116.168 us; speedup 1.0000x reference)
//
#include <hip/hip_runtime.h>
#include <math.h>

#define DD 768
#define NN 64
#define SS 512
#define BB 4

__device__ __forceinline__ float sigmf(float v) { return 1.0f / (1.0f + expf(-v)); }

// ---- DPP add helper (bound_ctrl=0-fill) ----
template <int CTRL>
__device__ __forceinline__ float dppadd(float v) {
    int s = __builtin_amdgcn_update_dpp(0, __float_as_int(v), CTRL, 0xF, 0xF, true);
    return v + __int_as_float(s);
}
// sum within each 16-lane row; result valid in lane 15 of each row
__device__ __forceinline__ float row_sum15(float v) {
    v = dppadd<0x111>(v);  // row_shr:1
    v = dppadd<0x112>(v);  // row_shr:2
    v = dppadd<0x114>(v);  // row_shr:4
    v = dppadd<0x118>(v);  // row_shr:8
    return v;
}
// full 64-lane sum, valid in lane 63 (for fallback kernel)
__device__ __forceinline__ float wave_sum63(float v) {
    v = row_sum15(v);
    v = dppadd<0x142>(v);  // row_bcast:15
    v = dppadd<0x143>(v);  // row_bcast:31
    return v;
}

// ---- fused prep (blocks 0..11) + x-transpose (blocks 12..395) ----
__global__ __launch_bounds__(256) void prep_xpose_kernel(const float* __restrict__ Braw,
                                                         const float* __restrict__ graw,
                                                         const float* __restrict__ x,
                                                         float* __restrict__ BwT,
                                                         float* __restrict__ gamma_s,
                                                         float* __restrict__ xT) {
    __shared__ float tile[64][65];
    int tx = threadIdx.x & 63;
    int tq = threadIdx.x >> 6;  // 0..3
    if (blockIdx.x < 12) {
        int d0 = blockIdx.x * 64;
#pragma unroll
        for (int i = 0; i < 16; ++i) {
            int n = tq + i * 4;
            tile[n][tx] = sigmf(Braw[n * DD + d0 + tx]);  // coalesced over d
        }
        __syncthreads();
#pragma unroll
        for (int i = 0; i < 16; ++i) {
            int dl = tq + i * 4;
            BwT[(d0 + dl) * NN + tx] = tile[tx][dl];      // coalesced over n
        }
        int gi = blockIdx.x * 256 + threadIdx.x;
        if (gi < DD) gamma_s[gi] = sigmf(graw[gi]);
    } else {
        int bidx = blockIdx.x - 12;        // 0..383
        int b  = bidx / 96;
        int r  = bidx - b * 96;
        int t0 = (r / 12) * 64;
        int d0 = (r % 12) * 64;
#pragma unroll
        for (int i = 0; i < 16; ++i) {
            int t = tq + i * 4;
            tile[t][tx] = x[((size_t)b * SS + t0 + t) * DD + d0 + tx];
        }
        __syncthreads();
#pragma unroll
        for (int i = 0; i < 16; ++i) {
            int dl = tq + i * 4;
            xT[((size_t)b * DD + d0 + dl) * SS + t0 + tx] = tile[tx][dl];
        }
    }
}

// ---- phase 1 (R4-proven): inp[r][n] = sum_d x[r][d] * BwT[d][n] ----
__global__ __launch_bounds__(256) void inp_kernel(const float* __restrict__ x,
                                                  const float* __restrict__ BwT,
                                                  float* __restrict__ inp) {
    int wid  = (blockIdx.x * 256 + threadIdx.x) >> 6;  // row 0..2047
    int lane = threadIdx.x & 63;
    int g = lane >> 4;
    int q = lane & 15;
    const float*  xr  = x + (size_t)wid * DD;
    const float4* bw4 = (const float4*)BwT + q;        // element d*16 + q

    float4 Aw0, Aw1, Aw2, Aw3; float Ax0, Ax1, Ax2, Ax3;
    float4 Bw0, Bw1, Bw2, Bw3; float Bx0, Bx1, Bx2, Bx3;
    float4 Cw0, Cw1, Cw2, Cw3; float Cx0, Cx1, Cx2, Cx3;
    float4 Dw0, Dw1, Dw2, Dw3; float Dx0, Dx1, Dx2, Dx3;

#define IPREF(P, C0)                                                     \
    {                                                                    \
        int cc_ = ((C0) < 48) ? (C0) : 0;                                \
        P##w0 = bw4[(16 * cc_ + 0 + g) * 16];                            \
        P##w1 = bw4[(16 * cc_ + 4 + g) * 16];                            \
        P##w2 = bw4[(16 * cc_ + 8 + g) * 16];                            \
        P##w3 = bw4[(16 * cc_ + 12 + g) * 16];                           \
        P##x0 = xr[16 * cc_ + 0 + g];                                    \
        P##x1 = xr[16 * cc_ + 4 + g];                                    \
        P##x2 = xr[16 * cc_ + 8 + g];                                    \
        P##x3 = xr[16 * cc_ + 12 + g];                                   \
    }
#define IFMA(W, X)                       \
    acc.x = fmaf(X, W.x, acc.x);         \
    acc.y = fmaf(X, W.y, acc.y);         \
    acc.z = fmaf(X, W.z, acc.z);         \
    acc.w = fmaf(X, W.w, acc.w);
#define ICOMP(P)                         \
    IFMA(P##w0, P##x0) IFMA(P##w1, P##x1) IFMA(P##w2, P##x2) IFMA(P##w3, P##x3)

    IPREF(A, 0) IPREF(B, 1) IPREF(C, 2) IPREF(D, 3)

    float4 acc = {0.f, 0.f, 0.f, 0.f};
    for (int c = 0; c < 48; c += 4) {
        ICOMP(A) IPREF(A, c + 4)
        ICOMP(B) IPREF(B, c + 5)
        ICOMP(C) IPREF(C, c + 6)
        ICOMP(D) IPREF(D, c + 7)
    }

#pragma unroll
    for (int off = 16; off <= 32; off <<= 1) {
        acc.x += __shfl_xor(acc.x, off, 64);
        acc.y += __shfl_xor(acc.y, off, 64);
        acc.z += __shfl_xor(acc.z, off, 64);
        acc.w += __shfl_xor(acc.w, off, 64);
    }
    if (lane < 16) ((float4*)(inp + (size_t)wid * NN))[q] = acc;
}

// ---- phase 2: scan v3. Wave = 4 d's x 64 n; lane dl=lane>>4, ng=lane&15;
// 4 n/lane. Chunks of 8 steps: 8 h-updates (serial h-chain only), then 8
// independent dot chains, then 8 independent DPP row-sum chains (ILP hides
// reduce latency), then 8 stores. A/B register buffers, 16-step lookahead.
__global__ __launch_bounds__(256) void scan_kernel(const float* __restrict__ xT,
                                                   const float* __restrict__ Araw,
                                                   const float* __restrict__ Craw,
                                                   const float* __restrict__ inp,
                                                   float* __restrict__ Y,
                                                   float* __restrict__ hfin) {
    int wid  = (blockIdx.x * 256 + threadIdx.x) >> 6;  // 0..767
    int lane = threadIdx.x & 63;
    int dl = lane >> 4;   // 0..3
    int ng = lane & 15;   // n-quad
    int b  = wid / 192;
    int d  = (wid - b * 192) * 4 + dl;

    float4 a4 = *((const float4*)(Araw + (size_t)d * NN) + ng);
    float4 c4 = *((const float4*)(Craw + (size_t)d * NN) + ng);
    a4.x = sigmf(a4.x); a4.y = sigmf(a4.y); a4.z = sigmf(a4.z); a4.w = sigmf(a4.w);
    c4.x = sigmf(c4.x); c4.y = sigmf(c4.y); c4.z = sigmf(c4.z); c4.w = sigmf(c4.w);

    const float4* ip4 = (const float4*)(inp + (size_t)(b * SS) * NN) + ng;  // idx t*16
    const float4* xt4 = (const float4*)(xT + ((size_t)b * DD + d) * SS);    // idx t/4
    float*        y_b = Y + (size_t)(b * SS) * DD + d;

    float4 Ai[8]; float4 Ax0, Ax1;
    float4 Bi[8]; float4 Bx0, Bx1;
    float4 h = {0.f, 0.f, 0.f, 0.f};

#define SPREF(P, T0)                                                       \
    {                                                                      \
        int tt_ = ((T0) < SS) ? (T0) : 0;                                  \
        _Pragma("unroll")                                                  \
        for (int i_ = 0; i_ < 8; ++i_) P##i[i_] = ip4[(tt_ + i_) * 16];    \
        P##x0 = xt4[(tt_ >> 2) + 0];                                       \
        P##x1 = xt4[(tt_ >> 2) + 1];                                       \
    }
#define SCHUNK(P, T0)                                                            \
    {                                                                            \
        const float xs_[8] = {P##x0.x, P##x0.y, P##x0.z, P##x0.w,                \
                              P##x1.x, P##x1.y, P##x1.z, P##x1.w};               \
        float4 hs_[8];                                                           \
        _Pragma("unroll")                                                        \
        for (int i_ = 0; i_ < 8; ++i_) {                                         \
            h.x = __builtin_amdgcn_fmed3f(fmaf(h.x, a4.x, P##i[i_].x * xs_[i_]), 0.f, 1.f); \
            h.y = __builtin_amdgcn_fmed3f(fmaf(h.y, a4.y, P##i[i_].y * xs_[i_]), 0.f, 1.f); \
            h.z = __builtin_amdgcn_fmed3f(fmaf(h.z, a4.z, P##i[i_].z * xs_[i_]), 0.f, 1.f); \
            h.w = __builtin_amdgcn_fmed3f(fmaf(h.w, a4.w, P##i[i_].w * xs_[i_]), 0.f, 1.f); \
            hs_[i_] = h;                                                         \
        }                                                                        \
        float ps_[8];                                                            \
        _Pragma("unroll")                                                        \
        for (int i_ = 0; i_ < 8; ++i_) {                                         \
            float p_ = hs_[i_].x * c4.x;                                         \
            p_ = fmaf(hs_[i_].y, c4.y, p_);                                      \
            p_ = fmaf(hs_[i_].z, c4.z, p_);                                      \
            p_ = fmaf(hs_[i_].w, c4.w, p_);                                      \
            ps_[i_] = p_;                                                        \
        }                                                                        \
        _Pragma("unroll")                                                        \
        for (int i_ = 0; i_ < 8; ++i_) ps_[i_] = row_sum15(ps_[i_]);             \
        if (ng == 15) {                                                          \
            _Pragma("unroll")                                                    \
            for (int i_ = 0; i_ < 8; ++i_) y_b[((T0) + i_) * DD] = ps_[i_];      \
        }                                                                        \
    }

    SPREF(A, 0)
    SPREF(B, 8)

    for (int t0 = 0; t0 < SS; t0 += 16) {
        SCHUNK(A, t0)
        SPREF(A, t0 + 16)
        SCHUNK(B, t0 + 8)
        SPREF(B, t0 + 24)
    }
    ((float4*)(hfin + ((size_t)b * DD + d) * NN))[ng] = h;
}

// ---- fallback scan (no xT; strided x reads; 1-n-per-lane mapping) ----
__global__ __launch_bounds__(256) void scan_fb_kernel(const float* __restrict__ x,
                                                      const float* __restrict__ Araw,
                                                      const float* __restrict__ Craw,
                                                      const float* __restrict__ inp,
                                                      float* __restrict__ Y,
                                                      float* __restrict__ hfin) {
    int wid  = (blockIdx.x * 256 + threadIdx.x) >> 6;
    int lane = threadIdx.x & 63;
    int b = wid / DD;
    int d = wid - b * DD;

    float a = sigmf(Araw[d * NN + lane]);
    float c = sigmf(Craw[d * NN + lane]);

    const float* ip_ptr = inp + (b * SS) * NN + lane;
    const float* x_ptr  = x   + (b * SS) * DD + d;
    float*       y_ptr  = Y   + (b * SS) * DD + d;

    float cip[8], cxv[8], nip[8], nxv[8];
#pragma unroll
    for (int i = 0; i < 8; ++i) {
        cip[i] = ip_ptr[i * NN];
        cxv[i] = x_ptr[i * DD];
    }
    float h = 0.f;
    for (int t0 = 0; t0 < SS; t0 += 8) {
        int tn = t0 + 8;
        if (tn >= SS) tn = SS - 8;
#pragma unroll
        for (int i = 0; i < 8; ++i) {
            nip[i] = ip_ptr[(tn + i) * NN];
            nxv[i] = x_ptr[(tn + i) * DD];
        }
#pragma unroll
        for (int i = 0; i < 8; ++i) {
            h = __builtin_amdgcn_fmed3f(fmaf(h, a, cip[i] * cxv[i]), 0.f, 1.f);
            float v = wave_sum63(h * c);
            if (lane == 63) y_ptr[(t0 + i) * DD] = v;
        }
#pragma unroll
        for (int i = 0; i < 8; ++i) { cip[i] = nip[i]; cxv[i] = nxv[i]; }
    }
    hfin[(size_t)wid * NN + lane] = h;
}

// ---- phase 3: in-place layernorm + gamma + residual + clip (float4) ----
__global__ __launch_bounds__(256) void ln_kernel(const float* __restrict__ x,
                                                 const float* __restrict__ gamma_s,
                                                 float* __restrict__ out) {
    int wid  = (blockIdx.x * 256 + threadIdx.x) >> 6;  // row 0..2047
    int lane = threadIdx.x & 63;
    float*       yr = out + (size_t)wid * DD;
    const float* xr = x   + (size_t)wid * DD;

    float4 y0 = ((const float4*)yr)[lane * 3 + 0];
    float4 y1 = ((const float4*)yr)[lane * 3 + 1];
    float4 y2 = ((const float4*)yr)[lane * 3 + 2];

    float s = ((y0.x + y0.y) + (y0.z + y0.w)) + ((y1.x + y1.y) + (y1.z + y1.w)) +
              ((y2.x + y2.y) + (y2.z + y2.w));
#pragma unroll
    for (int off = 32; off; off >>= 1) s += __shfl_xor(s, off, 64);
    float mu = s * (1.f / 768.f);

    float q = 0.f;
#define QACC(v)                 \
    {                           \
        float d0_ = (v) - mu;   \
        q = fmaf(d0_, d0_, q);  \
    }
    QACC(y0.x) QACC(y0.y) QACC(y0.z) QACC(y0.w)
    QACC(y1.x) QACC(y1.y) QACC(y1.z) QACC(y1.w)
    QACC(y2.x) QACC(y2.y) QACC(y2.z) QACC(y2.w)
#pragma unroll
    for (int off = 32; off; off >>= 1) q += __shfl_xor(q, off, 64);
    float inv = rsqrtf(q * (1.f / 768.f) + 1e-5f);

    float4 g0 = ((const float4*)gamma_s)[lane * 3 + 0];
    float4 g1 = ((const float4*)gamma_s)[lane * 3 + 1];
    float4 g2 = ((const float4*)gamma_s)[lane * 3 + 2];
    float4 x0 = ((const float4*)xr)[lane * 3 + 0];
    float4 x1 = ((const float4*)xr)[lane * 3 + 1];
    float4 x2 = ((const float4*)xr)[lane * 3 + 2];

#define FIN(yv, gv, xv) __builtin_amdgcn_fmed3f(fmaf((yv - mu) * inv, gv, xv), 0.f, 1.f)
    float4 o0, o1, o2;
    o0.x = FIN(y0.x, g0.x, x0.x); o0.y = FIN(y0.y, g0.y, x0.y);
    o0.z = FIN(y0.z, g0.z, x0.z); o0.w = FIN(y0.w, g0.w, x0.w);
    o1.x = FIN(y1.x, g1.x, x1.x); o1.y = FIN(y1.y, g1.y, x1.y);
    o1.z = FIN(y1.z, g1.z, x1.z); o1.w = FIN(y1.w, g1.w, x1.w);
    o2.x = FIN(y2.x, g2.x, x2.x); o2.y = FIN(y2.y, g2.y, x2.y);
    o2.z = FIN(y2.z, g2.z, x2.z); o2.w = FIN(y2.w, g2.w, x2.w);

    ((float4*)yr)[lane * 3 + 0] = o0;
    ((float4*)yr)[lane * 3 + 1] = o1;
    ((float4*)yr)[lane * 3 + 2] = o2;
}

extern "C" void kernel_launch(void* const* d_in, const int* in_sizes, int n_in,
                              void* d_out, int out_size, void* d_ws, size_t ws_size,
                              hipStream_t stream) {
    const float* x    = (const float*)d_in[0];  // [B,S,D]
    const float* Araw = (const float*)d_in[1];  // [D,N]
    const float* Braw = (const float*)d_in[2];  // [N,D]
    const float* Craw = (const float*)d_in[3];  // [D,N]
    const float* graw = (const float*)d_in[4];  // [D]

    float* out  = (float*)d_out;                // [B,S,D] then [B,D,N]
    float* hfin = out + (size_t)BB * SS * DD;

    float* ws      = (float*)d_ws;
    float* BwT     = ws;                                   // D*N   = 49152
    float* gamma_s = ws + DD * NN;                         // D     = 768
    float* inp     = ws + DD * NN + DD;                    // B*S*N = 131072
    float* xT      = ws + DD * NN + DD + BB * SS * NN;     // B*D*S = 1572864

    size_t need = (size_t)(DD * NN + DD + (size_t)BB * SS * NN + (size_t)BB * SS * DD) * sizeof(float);

    if (ws_size >= need) {
        prep_xpose_kernel<<<12 + BB * (SS / 64) * (DD / 64), 256, 0, stream>>>(
            Braw, graw, x, BwT, gamma_s, xT);
        inp_kernel<<<(BB * SS * NN) / 256, 256, 0, stream>>>(x, BwT, inp);
        scan_kernel<<<(BB * DD / 4) * 64 / 256, 256, 0, stream>>>(xT, Araw, Craw, inp, out, hfin);
    } else {
        prep_xpose_kernel<<<12, 256, 0, stream>>>(Braw, graw, x, BwT, gamma_s, xT);
        inp_kernel<<<(BB * SS * NN) / 256, 256, 0, stream>>>(x, BwT, inp);
        scan_fb_kernel<<<(BB * DD * NN) / 256, 256, 0, stream>>>(x, Araw, Craw, inp, out, hfin);
    }
    ln_kernel<<<(BB * SS * NN) / 256, 256, 0, stream>>>(x, gamma_s, out);
}

// Round 9
// 88.468 us; speedup vs baseline: 1.3131x; 1.3131x over previous
//
#include <hip/hip_runtime.h>
#include <math.h>

#define DD 768
#define NN 64
#define SS 512
#define BB 4
#define BSD (BB * SS * DD)

__device__ __forceinline__ float sigmf(float v) { return 1.0f / (1.0f + expf(-v)); }

// ---- DPP add helper (bound_ctrl=0-fill) ----
template <int CTRL>
__device__ __forceinline__ float dppadd(float v) {
    int s = __builtin_amdgcn_update_dpp(0, __float_as_int(v), CTRL, 0xF, 0xF, true);
    return v + __int_as_float(s);
}
// sum within each 16-lane row; result valid in lane 15 of each row
__device__ __forceinline__ float row_sum15(float v) {
    v = dppadd<0x111>(v);  // row_shr:1
    v = dppadd<0x112>(v);  // row_shr:2
    v = dppadd<0x114>(v);  // row_shr:4
    v = dppadd<0x118>(v);  // row_shr:8
    return v;
}
// full 64-lane sum, valid in lane 63 (fallback kernel)
__device__ __forceinline__ float wave_sum63(float v) {
    v = row_sum15(v);
    v = dppadd<0x142>(v);  // row_bcast:15
    v = dppadd<0x143>(v);  // row_bcast:31
    return v;
}

// ---- fused prep (blocks 0..11) + x-transpose (blocks 12..395) ----
__global__ __launch_bounds__(256) void prep_xpose_kernel(const float* __restrict__ Braw,
                                                         const float* __restrict__ graw,
                                                         const float* __restrict__ x,
                                                         float* __restrict__ BwT,
                                                         float* __restrict__ gamma_s,
                                                         float* __restrict__ xT) {
    __shared__ float tile[64][65];
    int tx = threadIdx.x & 63;
    int tq = threadIdx.x >> 6;  // 0..3
    if (blockIdx.x < 12) {
        int d0 = blockIdx.x * 64;
#pragma unroll
        for (int i = 0; i < 16; ++i) {
            int n = tq + i * 4;
            tile[n][tx] = sigmf(Braw[n * DD + d0 + tx]);  // coalesced over d
        }
        __syncthreads();
#pragma unroll
        for (int i = 0; i < 16; ++i) {
            int dl = tq + i * 4;
            BwT[(d0 + dl) * NN + tx] = tile[tx][dl];      // coalesced over n
        }
        int gi = blockIdx.x * 256 + threadIdx.x;
        if (gi < DD) gamma_s[gi] = sigmf(graw[gi]);
    } else {
        int bidx = blockIdx.x - 12;        // 0..383
        int b  = bidx / 96;
        int r  = bidx - b * 96;
        int t0 = (r / 12) * 64;
        int d0 = (r % 12) * 64;
#pragma unroll
        for (int i = 0; i < 16; ++i) {
            int t = tq + i * 4;
            tile[t][tx] = x[((size_t)b * SS + t0 + t) * DD + d0 + tx];
        }
        __syncthreads();
#pragma unroll
        for (int i = 0; i < 16; ++i) {
            int dl = tq + i * 4;
            xT[((size_t)b * DD + d0 + dl) * SS + t0 + tx] = tile[tx][dl];
        }
    }
}

// ---- phase 1 (R4-proven): inp[r][n] = sum_d x[r][d] * BwT[d][n] ----
__global__ __launch_bounds__(256) void inp_kernel(const float* __restrict__ x,
                                                  const float* __restrict__ BwT,
                                                  float* __restrict__ inp) {
    int wid  = (blockIdx.x * 256 + threadIdx.x) >> 6;  // row 0..2047
    int lane = threadIdx.x & 63;
    int g = lane >> 4;
    int q = lane & 15;
    const float*  xr  = x + (size_t)wid * DD;
    const float4* bw4 = (const float4*)BwT + q;        // element d*16 + q

    float4 Aw0, Aw1, Aw2, Aw3; float Ax0, Ax1, Ax2, Ax3;
    float4 Bw0, Bw1, Bw2, Bw3; float Bx0, Bx1, Bx2, Bx3;
    float4 Cw0, Cw1, Cw2, Cw3; float Cx0, Cx1, Cx2, Cx3;
    float4 Dw0, Dw1, Dw2, Dw3; float Dx0, Dx1, Dx2, Dx3;

#define IPREF(P, C0)                                                     \
    {                                                                    \
        int cc_ = ((C0) < 48) ? (C0) : 0;                                \
        P##w0 = bw4[(16 * cc_ + 0 + g) * 16];                            \
        P##w1 = bw4[(16 * cc_ + 4 + g) * 16];                            \
        P##w2 = bw4[(16 * cc_ + 8 + g) * 16];                            \
        P##w3 = bw4[(16 * cc_ + 12 + g) * 16];                           \
        P##x0 = xr[16 * cc_ + 0 + g];                                    \
        P##x1 = xr[16 * cc_ + 4 + g];                                    \
        P##x2 = xr[16 * cc_ + 8 + g];                                    \
        P##x3 = xr[16 * cc_ + 12 + g];                                   \
    }
#define IFMA(W, X)                       \
    acc.x = fmaf(X, W.x, acc.x);         \
    acc.y = fmaf(X, W.y, acc.y);         \
    acc.z = fmaf(X, W.z, acc.z);         \
    acc.w = fmaf(X, W.w, acc.w);
#define ICOMP(P)                         \
    IFMA(P##w0, P##x0) IFMA(P##w1, P##x1) IFMA(P##w2, P##x2) IFMA(P##w3, P##x3)

    IPREF(A, 0) IPREF(B, 1) IPREF(C, 2) IPREF(D, 3)

    float4 acc = {0.f, 0.f, 0.f, 0.f};
    for (int c = 0; c < 48; c += 4) {
        ICOMP(A) IPREF(A, c + 4)
        ICOMP(B) IPREF(B, c + 5)
        ICOMP(C) IPREF(C, c + 6)
        ICOMP(D) IPREF(D, c + 7)
    }

#pragma unroll
    for (int off = 16; off <= 32; off <<= 1) {
        acc.x += __shfl_xor(acc.x, off, 64);
        acc.y += __shfl_xor(acc.y, off, 64);
        acc.z += __shfl_xor(acc.z, off, 64);
        acc.w += __shfl_xor(acc.w, off, 64);
    }
    if (lane < 16) ((float4*)(inp + (size_t)wid * NN))[q] = acc;
}

// ---- phase 2: scan v4 (grid FIXED: 3072 waves = 768 blocks).
// Wave = 4 d's x 16 n's (n-quarter p); K=1 scalar h. Batched chunks of 8:
// 8 h-updates (serial 2-op chain), 8 independent h*c, 8 independent 4-DPP
// row sums, 8 partial stores. Partials -> 4 planes ypart[p], summed in ln4.
__global__ __launch_bounds__(256) void scan_kernel(const float* __restrict__ xT,
                                                   const float* __restrict__ Araw,
                                                   const float* __restrict__ Craw,
                                                   const float* __restrict__ inp,
                                                   float* __restrict__ ypart,
                                                   float* __restrict__ hfin) {
    int wid  = (blockIdx.x * 256 + threadIdx.x) >> 6;  // 0..3071
    int lane = threadIdx.x & 63;
    int dl = lane >> 4;        // 0..3
    int ng = lane & 15;
    int b   = wid / (192 * 4);           // 0..3
    int rem = wid - b * (192 * 4);
    int dg  = rem >> 2;                  // 0..191
    int p   = rem & 3;                   // n-quarter
    int d   = dg * 4 + dl;
    int n   = p * 16 + ng;

    float a = sigmf(Araw[(size_t)d * NN + n]);
    float c = sigmf(Craw[(size_t)d * NN + n]);

    const float*  ip_ptr = inp + (size_t)(b * SS) * NN + n;               // [t*64]
    const float4* xt4    = (const float4*)(xT + ((size_t)b * DD + d) * SS);
    float*        yp     = ypart + (size_t)p * BSD + (size_t)(b * SS) * DD + d;

    float Ai[8], Bi[8];
    float4 Ax0, Ax1, Bx0, Bx1;
    float h = 0.f;

#define SPREF(P, T0)                                                       \
    {                                                                      \
        int tt_ = ((T0) < SS) ? (T0) : 0;                                  \
        _Pragma("unroll")                                                  \
        for (int i_ = 0; i_ < 8; ++i_) P##i[i_] = ip_ptr[(tt_ + i_) * NN]; \
        P##x0 = xt4[(tt_ >> 2) + 0];                                       \
        P##x1 = xt4[(tt_ >> 2) + 1];                                       \
    }
#define SCHUNK(P, T0)                                                            \
    {                                                                            \
        const float xs_[8] = {P##x0.x, P##x0.y, P##x0.z, P##x0.w,                \
                              P##x1.x, P##x1.y, P##x1.z, P##x1.w};               \
        float hs_[8];                                                            \
        _Pragma("unroll")                                                        \
        for (int i_ = 0; i_ < 8; ++i_) {                                         \
            h = __builtin_amdgcn_fmed3f(fmaf(h, a, P##i[i_] * xs_[i_]), 0.f, 1.f); \
            hs_[i_] = h;                                                         \
        }                                                                        \
        float ps_[8];                                                            \
        _Pragma("unroll")                                                        \
        for (int i_ = 0; i_ < 8; ++i_) ps_[i_] = hs_[i_] * c;                    \
        _Pragma("unroll")                                                        \
        for (int i_ = 0; i_ < 8; ++i_) ps_[i_] = row_sum15(ps_[i_]);             \
        if (ng == 15) {                                                          \
            _Pragma("unroll")                                                    \
            for (int i_ = 0; i_ < 8; ++i_) yp[((T0) + i_) * DD] = ps_[i_];       \
        }                                                                        \
    }

    SPREF(A, 0)
    SPREF(B, 8)

    for (int t0 = 0; t0 < SS; t0 += 16) {
        SCHUNK(A, t0)
        SPREF(A, t0 + 16)
        SCHUNK(B, t0 + 8)
        SPREF(B, t0 + 24)
    }
    hfin[((size_t)b * DD + d) * NN + n] = h;
}

// ---- fallback scan (no xT/partials; strided x reads; 1-n-per-lane) ----
__global__ __launch_bounds__(256) void scan_fb_kernel(const float* __restrict__ x,
                                                      const float* __restrict__ Araw,
                                                      const float* __restrict__ Craw,
                                                      const float* __restrict__ inp,
                                                      float* __restrict__ Y,
                                                      float* __restrict__ hfin) {
    int wid  = (blockIdx.x * 256 + threadIdx.x) >> 6;
    int lane = threadIdx.x & 63;
    int b = wid / DD;
    int d = wid - b * DD;

    float a = sigmf(Araw[d * NN + lane]);
    float c = sigmf(Craw[d * NN + lane]);

    const float* ip_ptr = inp + (b * SS) * NN + lane;
    const float* x_ptr  = x   + (b * SS) * DD + d;
    float*       y_ptr  = Y   + (b * SS) * DD + d;

    float cip[8], cxv[8], nip[8], nxv[8];
#pragma unroll
    for (int i = 0; i < 8; ++i) {
        cip[i] = ip_ptr[i * NN];
        cxv[i] = x_ptr[i * DD];
    }
    float h = 0.f;
    for (int t0 = 0; t0 < SS; t0 += 8) {
        int tn = t0 + 8;
        if (tn >= SS) tn = SS - 8;
#pragma unroll
        for (int i = 0; i < 8; ++i) {
            nip[i] = ip_ptr[(tn + i) * NN];
            nxv[i] = x_ptr[(tn + i) * DD];
        }
#pragma unroll
        for (int i = 0; i < 8; ++i) {
            h = __builtin_amdgcn_fmed3f(fmaf(h, a, cip[i] * cxv[i]), 0.f, 1.f);
            float v = wave_sum63(h * c);
            if (lane == 63) y_ptr[(t0 + i) * DD] = v;
        }
#pragma unroll
        for (int i = 0; i < 8; ++i) { cip[i] = nip[i]; cxv[i] = nxv[i]; }
    }
    hfin[(size_t)wid * NN + lane] = h;
}

// ---- phase 3a: layernorm combining 4 partial planes ----
__global__ __launch_bounds__(256) void ln4_kernel(const float* __restrict__ x,
                                                  const float* __restrict__ gamma_s,
                                                  const float* __restrict__ ypart,
                                                  float* __restrict__ out) {
    int wid  = (blockIdx.x * 256 + threadIdx.x) >> 6;  // row 0..2047
    int lane = threadIdx.x & 63;
    const float4* p0 = (const float4*)(ypart + 0 * (size_t)BSD + (size_t)wid * DD);
    const float4* p1 = (const float4*)(ypart + 1 * (size_t)BSD + (size_t)wid * DD);
    const float4* p2 = (const float4*)(ypart + 2 * (size_t)BSD + (size_t)wid * DD);
    const float4* p3 = (const float4*)(ypart + 3 * (size_t)BSD + (size_t)wid * DD);
    const float*  xr = x + (size_t)wid * DD;

    float4 y0, y1, y2;
#define SUM4(DST, IDX)                                                        \
    {                                                                         \
        float4 a_ = p0[IDX], b_ = p1[IDX], c_ = p2[IDX], d_ = p3[IDX];        \
        DST.x = (a_.x + b_.x) + (c_.x + d_.x);                                \
        DST.y = (a_.y + b_.y) + (c_.y + d_.y);                                \
        DST.z = (a_.z + b_.z) + (c_.z + d_.z);                                \
        DST.w = (a_.w + b_.w) + (c_.w + d_.w);                                \
    }
    SUM4(y0, lane * 3 + 0)
    SUM4(y1, lane * 3 + 1)
    SUM4(y2, lane * 3 + 2)

    float s = ((y0.x + y0.y) + (y0.z + y0.w)) + ((y1.x + y1.y) + (y1.z + y1.w)) +
              ((y2.x + y2.y) + (y2.z + y2.w));
#pragma unroll
    for (int off = 32; off; off >>= 1) s += __shfl_xor(s, off, 64);
    float mu = s * (1.f / 768.f);

    float q = 0.f;
#define QACC(v)                 \
    {                           \
        float d0_ = (v) - mu;   \
        q = fmaf(d0_, d0_, q);  \
    }
    QACC(y0.x) QACC(y0.y) QACC(y0.z) QACC(y0.w)
    QACC(y1.x) QACC(y1.y) QACC(y1.z) QACC(y1.w)
    QACC(y2.x) QACC(y2.y) QACC(y2.z) QACC(y2.w)
#pragma unroll
    for (int off = 32; off; off >>= 1) q += __shfl_xor(q, off, 64);
    float inv = rsqrtf(q * (1.f / 768.f) + 1e-5f);

    float4 g0 = ((const float4*)gamma_s)[lane * 3 + 0];
    float4 g1 = ((const float4*)gamma_s)[lane * 3 + 1];
    float4 g2 = ((const float4*)gamma_s)[lane * 3 + 2];
    float4 x0 = ((const float4*)xr)[lane * 3 + 0];
    float4 x1 = ((const float4*)xr)[lane * 3 + 1];
    float4 x2 = ((const float4*)xr)[lane * 3 + 2];

#define FIN(yv, gv, xv) __builtin_amdgcn_fmed3f(fmaf((yv - mu) * inv, gv, xv), 0.f, 1.f)
    float4 o0, o1, o2;
    o0.x = FIN(y0.x, g0.x, x0.x); o0.y = FIN(y0.y, g0.y, x0.y);
    o0.z = FIN(y0.z, g0.z, x0.z); o0.w = FIN(y0.w, g0.w, x0.w);
    o1.x = FIN(y1.x, g1.x, x1.x); o1.y = FIN(y1.y, g1.y, x1.y);
    o1.z = FIN(y1.z, g1.z, x1.z); o1.w = FIN(y1.w, g1.w, x1.w);
    o2.x = FIN(y2.x, g2.x, x2.x); o2.y = FIN(y2.y, g2.y, x2.y);
    o2.z = FIN(y2.z, g2.z, x2.z); o2.w = FIN(y2.w, g2.w, x2.w);

    float4* orow = (float4*)(out + (size_t)wid * DD);
    orow[lane * 3 + 0] = o0;
    orow[lane * 3 + 1] = o1;
    orow[lane * 3 + 2] = o2;
}

// ---- phase 3b: in-place layernorm (fallback path; y already in out) ----
__global__ __launch_bounds__(256) void ln_kernel(const float* __restrict__ x,
                                                 const float* __restrict__ gamma_s,
                                                 float* __restrict__ out) {
    int wid  = (blockIdx.x * 256 + threadIdx.x) >> 6;
    int lane = threadIdx.x & 63;
    float*       yr = out + (size_t)wid * DD;
    const float* xr = x   + (size_t)wid * DD;

    float4 y0 = ((const float4*)yr)[lane * 3 + 0];
    float4 y1 = ((const float4*)yr)[lane * 3 + 1];
    float4 y2 = ((const float4*)yr)[lane * 3 + 2];

    float s = ((y0.x + y0.y) + (y0.z + y0.w)) + ((y1.x + y1.y) + (y1.z + y1.w)) +
              ((y2.x + y2.y) + (y2.z + y2.w));
#pragma unroll
    for (int off = 32; off; off >>= 1) s += __shfl_xor(s, off, 64);
    float mu = s * (1.f / 768.f);

    float q = 0.f;
    QACC(y0.x) QACC(y0.y) QACC(y0.z) QACC(y0.w)
    QACC(y1.x) QACC(y1.y) QACC(y1.z) QACC(y1.w)
    QACC(y2.x) QACC(y2.y) QACC(y2.z) QACC(y2.w)
#pragma unroll
    for (int off = 32; off; off >>= 1) q += __shfl_xor(q, off, 64);
    float inv = rsqrtf(q * (1.f / 768.f) + 1e-5f);

    float4 g0 = ((const float4*)gamma_s)[lane * 3 + 0];
    float4 g1 = ((const float4*)gamma_s)[lane * 3 + 1];
    float4 g2 = ((const float4*)gamma_s)[lane * 3 + 2];
    float4 x0 = ((const float4*)xr)[lane * 3 + 0];
    float4 x1 = ((const float4*)xr)[lane * 3 + 1];
    float4 x2 = ((const float4*)xr)[lane * 3 + 2];

    float4 o0, o1, o2;
    o0.x = FIN(y0.x, g0.x, x0.x); o0.y = FIN(y0.y, g0.y, x0.y);
    o0.z = FIN(y0.z, g0.z, x0.z); o0.w = FIN(y0.w, g0.w, x0.w);
    o1.x = FIN(y1.x, g1.x, x1.x); o1.y = FIN(y1.y, g1.y, x1.y);
    o1.z = FIN(y1.z, g1.z, x1.z); o1.w = FIN(y1.w, g1.w, x1.w);
    o2.x = FIN(y2.x, g2.x, x2.x); o2.y = FIN(y2.y, g2.y, x2.y);
    o2.z = FIN(y2.z, g2.z, x2.z); o2.w = FIN(y2.w, g2.w, x2.w);

    ((float4*)yr)[lane * 3 + 0] = o0;
    ((float4*)yr)[lane * 3 + 1] = o1;
    ((float4*)yr)[lane * 3 + 2] = o2;
}

extern "C" void kernel_launch(void* const* d_in, const int* in_sizes, int n_in,
                              void* d_out, int out_size, void* d_ws, size_t ws_size,
                              hipStream_t stream) {
    const float* x    = (const float*)d_in[0];  // [B,S,D]
    const float* Araw = (const float*)d_in[1];  // [D,N]
    const float* Braw = (const float*)d_in[2];  // [N,D]
    const float* Craw = (const float*)d_in[3];  // [D,N]
    const float* graw = (const float*)d_in[4];  // [D]

    float* out  = (float*)d_out;                // [B,S,D] then [B,D,N]
    float* hfin = out + (size_t)BSD;

    float* ws      = (float*)d_ws;
    float* BwT     = ws;                                   // D*N   = 49152
    float* gamma_s = ws + DD * NN;                         // D     = 768
    float* inp     = ws + DD * NN + DD;                    // B*S*N = 131072
    float* xT      = ws + DD * NN + DD + BB * SS * NN;     // B*D*S = 1572864
    float* ypart   = xT + (size_t)BSD;                     // 4*B*S*D = 6291456

    size_t base_need = (size_t)(DD * NN + DD + BB * SS * NN) * sizeof(float);
    size_t full_need = base_need + (size_t)BSD * 5 * sizeof(float);

    if (ws_size >= full_need) {
        prep_xpose_kernel<<<12 + BB * (SS / 64) * (DD / 64), 256, 0, stream>>>(
            Braw, graw, x, BwT, gamma_s, xT);
        inp_kernel<<<(BB * SS * NN) / 256, 256, 0, stream>>>(x, BwT, inp);
        // 3072 waves = (B=4) * (D/4=192 d-groups) * (4 n-quarters); 64 thr/wave
        scan_kernel<<<(BB * (DD / 4) * 4 * 64) / 256, 256, 0, stream>>>(
            xT, Araw, Craw, inp, ypart, hfin);
        ln4_kernel<<<(BB * SS * NN) / 256, 256, 0, stream>>>(x, gamma_s, ypart, out);
    } else {
        prep_xpose_kernel<<<12, 256, 0, stream>>>(Braw, graw, x, BwT, gamma_s, xT);
        inp_kernel<<<(BB * SS * NN) / 256, 256, 0, stream>>>(x, BwT, inp);
        scan_fb_kernel<<<(BB * DD * NN) / 256, 256, 0, stream>>>(x, Araw, Craw, inp, out, hfin);
        ln_kernel<<<(BB * SS * NN) / 256, 256, 0, stream>>>(x, gamma_s, out);
    }
}